// Round 2
// baseline (127.088 us; speedup 1.0000x reference)
//
#include <hip/hip_runtime.h>

#define S 128
#define DFEAT 150528
#define BK 64
#define NCHUNK (DFEAT / BK)   // 2352
#define GRIDG 1024

typedef short short8 __attribute__((ext_vector_type(8)));
typedef float f32x4 __attribute__((ext_vector_type(4)));

__device__ __forceinline__ unsigned short f2bf(float f) {
    unsigned u = __builtin_bit_cast(unsigned, f);
    unsigned r = (u + 0x7FFFu + ((u >> 16) & 1u)) >> 16;   // RNE
    return (unsigned short)r;
}

__device__ __forceinline__ unsigned long long pack4(float4 v) {
    return (unsigned long long)f2bf(v.x)
         | ((unsigned long long)f2bf(v.y) << 16)
         | ((unsigned long long)f2bf(v.z) << 32)
         | ((unsigned long long)f2bf(v.w) << 48);
}

// K1: partial Gram over this block's K-chunks, collapsed in-block to
// diagonal-bin sums (atomicAdd to diag[255]); plus row sum-of-squares.
// A = clip2 (matrix rows, x), B = clip1 (matrix cols, y).
__global__ __launch_bounds__(512, 1) void k1_gram(
    const float* __restrict__ A,
    const float* __restrict__ B,
    float* __restrict__ diag,       // [255]
    float* __restrict__ sqBuf,      // [256]: [0..127]=||a_i||^2, [128..255]=||b_j||^2
    int G)
{
    __shared__ alignas(16) char lds[32768];  // As bf16[128][64] @0, Bs @16384

    const int t  = threadIdx.x;
    const int g  = blockIdx.x;
    const int r  = t >> 2;      // row this thread stages (0..127)
    const int q4 = t & 3;

    const float4* __restrict__ arow = (const float4*)(A + (size_t)r * DFEAT);
    const float4* __restrict__ brow = (const float4*)(B + (size_t)r * DFEAT);

    const int w    = t >> 6;
    const int lane = t & 63;
    const int wr   = w >> 2;          // 0..1  (64 rows each)
    const int wc   = w & 3;           // 0..3  (32 cols each)
    const int lrow = lane & 15;
    const int lk   = (lane >> 4) * 8; // k offset within 32-wide MFMA step

    f32x4 acc[4][2];
    #pragma unroll
    for (int i = 0; i < 4; i++)
        #pragma unroll
        for (int j = 0; j < 2; j++) {
            f32x4 z = {0.f, 0.f, 0.f, 0.f};
            acc[i][j] = z;
        }

    float sqa = 0.f, sqb = 0.f;

    float4 va[4], vb[4];
    int c = g;
    if (c < NCHUNK) {
        #pragma unroll
        for (int it = 0; it < 4; it++) {
            int idx = c * 16 + it * 4 + q4;
            va[it] = arow[idx];
            vb[it] = brow[idx];
        }
    }

    while (c < NCHUNK) {
        __syncthreads();   // previous MFMA phase done reading LDS
        // stage chunk c (registers -> bf16 -> swizzled LDS) + sq accumulate
        #pragma unroll
        for (int it = 0; it < 4; it++) {
            int fq   = it * 4 + q4;
            int addr = (r * 128 + fq * 8) ^ ((r & 7) << 4);
            float4 v = va[it];
            *(unsigned long long*)(lds + addr) = pack4(v);
            sqa += v.x*v.x + v.y*v.y + v.z*v.z + v.w*v.w;
            v = vb[it];
            *(unsigned long long*)(lds + 16384 + addr) = pack4(v);
            sqb += v.x*v.x + v.y*v.y + v.z*v.z + v.w*v.w;
        }
        // prefetch next chunk into registers (in flight during MFMA phase)
        int cn = c + G;
        if (cn < NCHUNK) {
            #pragma unroll
            for (int it = 0; it < 4; it++) {
                int idx = cn * 16 + it * 4 + q4;
                va[it] = arow[idx];
                vb[it] = brow[idx];
            }
        }
        __syncthreads();   // LDS tile ready
        #pragma unroll
        for (int kk = 0; kk < 2; kk++) {
            short8 bfrag[2], afrag[4];
            #pragma unroll
            for (int tn = 0; tn < 2; tn++) {
                int n   = wc * 32 + tn * 16 + lrow;
                int off = (n * 128 + (kk * 32 + lk) * 2) ^ ((n & 7) << 4);
                bfrag[tn] = *(const short8*)(lds + 16384 + off);
            }
            #pragma unroll
            for (int tm = 0; tm < 4; tm++) {
                int m   = wr * 64 + tm * 16 + lrow;
                int off = (m * 128 + (kk * 32 + lk) * 2) ^ ((m & 7) << 4);
                afrag[tm] = *(const short8*)(lds + off);
            }
            #pragma unroll
            for (int tm = 0; tm < 4; tm++)
                #pragma unroll
                for (int tn = 0; tn < 2; tn++)
                    acc[tm][tn] = __builtin_amdgcn_mfma_f32_16x16x32_bf16(
                        afrag[tm], bfrag[tn], acc[tm][tn], 0, 0, 0);
        }
        c = cn;
    }

    // collapse this block's partial tile into diagonal bins.
    // C/D layout: col=lane&15, row=(lane>>4)*4+reg
    __syncthreads();                       // done reading lds as tile
    float* ldsDiag = (float*)lds;
    for (int i = t; i < 255; i += 512) ldsDiag[i] = 0.f;
    __syncthreads();
    const int crow = (lane >> 4) * 4;
    const int ccol = lane & 15;
    #pragma unroll
    for (int tm = 0; tm < 4; tm++) {
        #pragma unroll
        for (int tn = 0; tn < 2; tn++) {
            int row0 = wr * 64 + tm * 16 + crow;
            int col  = wc * 32 + tn * 16 + ccol;
            int bin0 = 127 - row0 + col;   // then -1 per rg
            #pragma unroll
            for (int rg = 0; rg < 4; rg++)
                atomicAdd(&ldsDiag[bin0 - rg], acc[tm][tn][rg]);
        }
    }
    __syncthreads();
    for (int i = t; i < 255; i += 512) atomicAdd(&diag[i], ldsDiag[i]);

    // reduce sq over the 4 lanes sharing a row, then accumulate globally
    sqa += __shfl_down(sqa, 2); sqa += __shfl_down(sqa, 1);
    sqb += __shfl_down(sqb, 2); sqb += __shfl_down(sqb, 1);
    if (q4 == 0) {
        atomicAdd(&sqBuf[r], sqa);
        atomicAdd(&sqBuf[128 + r], sqb);
    }
}

// K3: combine diag gram sums with sq-norm terms -> 129 outputs.
__global__ void k3_out(const float* __restrict__ sqBuf,
                       const float* __restrict__ diag,
                       float* __restrict__ out)
{
    int o = threadIdx.x;
    if (o >= 129) return;
    int d   = o - 64;
    int ad  = d < 0 ? -d : d;
    int cnt = 128 - ad;
    int i0  = d < 0 ? -d : 0;
    float sq = 0.f;
    for (int tt = 0; tt < cnt; tt++) {
        int i = i0 + tt;
        sq += sqBuf[i] + sqBuf[128 + i + d];
    }
    float gv = diag[63 + o];
    out[o] = -((sq - 2.f * gv) * (1.0f / (float)DFEAT)) * 1e13f / (float)cnt;
}

extern "C" void kernel_launch(void* const* d_in, const int* in_sizes, int n_in,
                              void* d_out, int out_size, void* d_ws, size_t ws_size,
                              hipStream_t stream) {
    const float* clip1 = (const float*)d_in[0];  // b: matrix cols (y)
    const float* clip2 = (const float*)d_in[1];  // a: matrix rows (x)
    float* out = (float*)d_out;

    float* sqBuf = (float*)d_ws;          // 256 floats
    float* diag  = sqBuf + 256;           // 255 floats

    hipMemsetAsync(d_ws, 0, 4096, stream);  // zero sqBuf + diag
    k1_gram<<<dim3(GRIDG), dim3(512), 0, stream>>>(clip2, clip1, diag, sqBuf, GRIDG);
    k3_out<<<dim3(1), dim3(256), 0, stream>>>(sqBuf, diag, out);
}

// Round 3
// 93.777 us; speedup vs baseline: 1.3552x; 1.3552x over previous
//
#include <hip/hip_runtime.h>

#define S 128
#define DFEAT 150528
#define BK 128
#define NCHUNK (DFEAT / BK)    // 1176
#define NF4ROW (DFEAT / 4)     // 37632 float4 per row
#define GRIDG 256

typedef short short8 __attribute__((ext_vector_type(8)));
typedef float f32x4 __attribute__((ext_vector_type(4)));

__device__ __forceinline__ unsigned short f2bf(float f) {
    unsigned u = __builtin_bit_cast(unsigned, f);
    return (unsigned short)((u + 0x7FFFu + ((u >> 16) & 1u)) >> 16);   // RNE
}
__device__ __forceinline__ uint2 pack4(float4 v) {
    uint2 r;
    r.x = (unsigned)f2bf(v.x) | ((unsigned)f2bf(v.y) << 16);
    r.y = (unsigned)f2bf(v.z) | ((unsigned)f2bf(v.w) << 16);
    return r;
}

// K1: full 128x128 Gram via bf16 MFMA, K-split over blocks; per block the
// partial tile is collapsed to 255 diagonal sums (1 atomic per bin).
// A = clip2 (matrix rows, x), B = clip1 (matrix cols, y).
__global__ __launch_bounds__(1024, 4) void k1_gram(
    const float* __restrict__ A,
    const float* __restrict__ B,
    float* __restrict__ diag,      // [255]
    float* __restrict__ sqBuf)     // [256]: [0..127]=||a||^2, [128..255]=||b||^2
{
    __shared__ alignas(16) char lds[65536];  // As bf16[128][128] @0, Bs @32768

    const int t = threadIdx.x;
    const int g = blockIdx.x;
    const int w = t >> 6, l = t & 63;
    const int h = l >> 5, li = l & 31;       // half-wave, idx in half

    // staging: thread owns 4 fixed rows rj = w*2 + h + 32j; per chunk it
    // loads float4 at column li -> each half-wave = one contiguous 512B span.
    int rowj[4], roff[4], wa[4];
    #pragma unroll
    for (int j = 0; j < 4; j++) {
        int r = w * 2 + h + 32 * j;
        rowj[j] = r;
        roff[j] = r * NF4ROW;                              // float4 units
        wa[j]   = (r * 256 + 8 * li) ^ ((r & 7) << 4);     // swizzled LDS byte
    }
    const float4* __restrict__ af4 = (const float4*)A;
    const float4* __restrict__ bf4 = (const float4*)B;

    const int wrow = w >> 2, wcol = w & 3;   // 4x4 wave grid, 32x32 tile each
    const int lrow = l & 15;

    f32x4 acc[2][2];
    #pragma unroll
    for (int i = 0; i < 2; i++)
        #pragma unroll
        for (int j = 0; j < 2; j++) { f32x4 z = {0.f,0.f,0.f,0.f}; acc[i][j] = z; }

    float sa[4] = {0.f,0.f,0.f,0.f}, sb[4] = {0.f,0.f,0.f,0.f};

    // prologue: load chunk c0 = g (every block has >= 4 chunks)
    int c = g;
    float4 pa[4], pb[4];
    #pragma unroll
    for (int j = 0; j < 4; j++) {
        pa[j] = af4[roff[j] + c * 32 + li];
        pb[j] = bf4[roff[j] + c * 32 + li];
    }

    while (c < NCHUNK) {
        int cn = c + GRIDG;
        // stage regs -> bf16 LDS; issue next-chunk load right after each reg
        // is consumed so global loads stay in flight across the whole phase.
        #pragma unroll
        for (int j = 0; j < 4; j++) {
            float4 v = pa[j];
            *(uint2*)(lds + wa[j]) = pack4(v);
            sa[j] += v.x*v.x + v.y*v.y + v.z*v.z + v.w*v.w;
            if (cn < NCHUNK) pa[j] = af4[roff[j] + cn * 32 + li];
            v = pb[j];
            *(uint2*)(lds + 32768 + wa[j]) = pack4(v);
            sb[j] += v.x*v.x + v.y*v.y + v.z*v.z + v.w*v.w;
            if (cn < NCHUNK) pb[j] = bf4[roff[j] + cn * 32 + li];
        }
        asm volatile("s_waitcnt lgkmcnt(0)" ::: "memory");  // ds_writes done
        __builtin_amdgcn_s_barrier();                       // tile visible

        #pragma unroll
        for (int kk = 0; kk < 4; kk++) {
            int kb = kk * 64 + (l >> 4) * 16;               // byte offset in row
            short8 af[2], bfr[2];
            #pragma unroll
            for (int tm = 0; tm < 2; tm++) {
                int m = wrow * 32 + tm * 16 + lrow;
                af[tm] = *(const short8*)(lds + ((m * 256 + kb) ^ ((m & 7) << 4)));
            }
            #pragma unroll
            for (int tn = 0; tn < 2; tn++) {
                int n = wcol * 32 + tn * 16 + lrow;
                bfr[tn] = *(const short8*)(lds + 32768 + ((n * 256 + kb) ^ ((n & 7) << 4)));
            }
            #pragma unroll
            for (int tm = 0; tm < 2; tm++)
                #pragma unroll
                for (int tn = 0; tn < 2; tn++)
                    acc[tm][tn] = __builtin_amdgcn_mfma_f32_16x16x32_bf16(
                        af[tm], bfr[tn], acc[tm][tn], 0, 0, 0);
        }
        __builtin_amdgcn_s_barrier();   // reads consumed; LDS reusable
        c = cn;
    }

    // ---- epilogue: tile -> LDS f32, then 255 diagonal sums ----
    float* ldsF = (float*)lds;          // [128][128] f32 = 64KB
    const int crow = (l >> 4) * 4, ccol = l & 15;
    #pragma unroll
    for (int tm = 0; tm < 2; tm++)
        #pragma unroll
        for (int tn = 0; tn < 2; tn++) {
            int row0 = wrow * 32 + tm * 16 + crow;
            int col  = wcol * 32 + tn * 16 + ccol;
            #pragma unroll
            for (int rg = 0; rg < 4; rg++)
                ldsF[(row0 + rg) * 128 + col] = acc[tm][tn][rg];
        }
    asm volatile("s_waitcnt lgkmcnt(0)" ::: "memory");
    __builtin_amdgcn_s_barrier();

    if (t < 255) {
        int del = t - 127;                       // col - row
        int r0  = del < 0 ? -del : 0;
        int len = 128 - (del < 0 ? -del : del);
        float s = 0.f;
        for (int i = 0; i < len; i++) {
            int r = r0 + i;
            s += ldsF[r * 128 + r + del];        // stride 129: conflict-free
        }
        atomicAdd(&diag[t], s);
    }

    // row sum-of-squares: reduce over the 32 lanes sharing each row
    #pragma unroll
    for (int j = 0; j < 4; j++) {
        float va = sa[j], vb = sb[j];
        #pragma unroll
        for (int m = 16; m >= 1; m >>= 1) {
            va += __shfl_xor(va, m);
            vb += __shfl_xor(vb, m);
        }
        if (li == 0) {
            atomicAdd(&sqBuf[rowj[j]], va);
            atomicAdd(&sqBuf[128 + rowj[j]], vb);
        }
    }
}

// K3: combine diag gram sums with sq-norm terms -> 129 outputs.
__global__ void k3_out(const float* __restrict__ sqBuf,
                       const float* __restrict__ diag,
                       float* __restrict__ out)
{
    int o = threadIdx.x;
    if (o >= 129) return;
    int d   = o - 64;
    int ad  = d < 0 ? -d : d;
    int cnt = 128 - ad;
    int i0  = d < 0 ? -d : 0;
    float sq = 0.f;
    for (int tt = 0; tt < cnt; tt++) {
        int i = i0 + tt;
        sq += sqBuf[i] + sqBuf[128 + i + d];
    }
    float gv = diag[63 + o];
    out[o] = -((sq - 2.f * gv) * (1.0f / (float)DFEAT)) * 1e13f / (float)cnt;
}

extern "C" void kernel_launch(void* const* d_in, const int* in_sizes, int n_in,
                              void* d_out, int out_size, void* d_ws, size_t ws_size,
                              hipStream_t stream) {
    const float* clip1 = (const float*)d_in[0];  // b: matrix cols (y)
    const float* clip2 = (const float*)d_in[1];  // a: matrix rows (x)
    float* out = (float*)d_out;

    float* sqBuf = (float*)d_ws;          // 256 floats
    float* diag  = sqBuf + 256;           // 255 floats

    hipMemsetAsync(d_ws, 0, 4096, stream);
    k1_gram<<<dim3(GRIDG), dim3(1024), 0, stream>>>(clip2, clip1, diag, sqBuf);
    k3_out<<<dim3(1), dim3(256), 0, stream>>>(sqBuf, diag, out);
}

// Round 4
// 60.620 us; speedup vs baseline: 2.0965x; 1.5470x over previous
//
#include <hip/hip_runtime.h>

#define S 128
#define DFEAT 150528
#define RSB ((size_t)DFEAT * 4)   // row stride bytes = 602112
#define BK 32
#define NCHUNK (DFEAT / BK)       // 4704
#define GRID 256

typedef short short8 __attribute__((ext_vector_type(8)));
typedef float f32x4 __attribute__((ext_vector_type(4)));

__device__ __forceinline__ unsigned short f2bf(float f) {
    unsigned u = __builtin_bit_cast(unsigned, f);
    return (unsigned short)((u + 0x7FFFu + ((u >> 16) & 1u)) >> 16);   // RNE
}

__device__ __forceinline__ short8 cvt8(f32x4 a, f32x4 b) {
    short8 r;
    r[0] = (short)f2bf(a[0]); r[1] = (short)f2bf(a[1]);
    r[2] = (short)f2bf(a[2]); r[3] = (short)f2bf(a[3]);
    r[4] = (short)f2bf(b[0]); r[5] = (short)f2bf(b[1]);
    r[6] = (short)f2bf(b[2]); r[7] = (short)f2bf(b[3]);
    return r;
}

__device__ __forceinline__ void gload16(const void* g, void* l) {
    __builtin_amdgcn_global_load_lds(
        (const __attribute__((address_space(1))) unsigned int*)g,
        (__attribute__((address_space(3))) unsigned int*)(void*)l,
        16, 0, 0);
}

// K1: 128x128 Gram, K-split over 256 blocks. fp32 tiles staged direct-to-LDS
// via global_load_lds (pre-swizzled source addresses, linear LDS dest);
// fragments read fp32+swizzle, converted to bf16 in regs, MFMA accumulate.
// Per block: partial tile collapsed to 255 diagonal sums. A=clip2, B=clip1.
__global__ __launch_bounds__(1024, 4) void k1_gram(
    const char* __restrict__ A, const char* __restrict__ B,
    float* __restrict__ diag, float* __restrict__ sqBuf)
{
    __shared__ alignas(16) char lds[65536];  // 2 bufs x (A 16K + B 16K)

    const int t = threadIdx.x, g = blockIdx.x;
    const int w = t >> 6, l = t & 63;

    // ---- staging geometry: wave w stages rows 8w..8w+7 of A and B ----
    // one global_load_lds instr = 64 lanes x 16B = 8 rows x 128B (one BK=32
    // chunk-row). LDS dest linear; source slot pre-swizzled s' = s ^ (r&7).
    const int sr   = l >> 3;            // row within wave's group == r&7
    const int sslt = (l & 7) ^ sr;      // pre-swizzled 16B slot in row chunk
    const int myrow = 8 * w + sr;
    const size_t srcOff = (size_t)myrow * RSB + (size_t)(sslt << 4);

    // ---- MFMA geometry: 4x4 wave grid, 32x32 tile per wave ----
    const int wrow = w >> 2, wcol = w & 3;
    const int fr = l & 15, grp = l >> 4;

    f32x4 acc[2][2];
    #pragma unroll
    for (int i = 0; i < 2; i++)
        #pragma unroll
        for (int j = 0; j < 2; j++) { f32x4 z = {0.f,0.f,0.f,0.f}; acc[i][j] = z; }

    float sqa = 0.f, sqb = 0.f;

    int c = g;
    // prologue: stage chunk c into buffer 0
    gload16(A + srcOff + (size_t)c * 128, &lds[w * 1024]);
    gload16(B + srcOff + (size_t)c * 128, &lds[16384 + w * 1024]);

    int p = 0;
    while (c < NCHUNK) {
        int cn = c + GRID;
        if (cn < NCHUNK) {
            int q = (p ^ 1) * 32768;
            gload16(A + srcOff + (size_t)cn * 128, &lds[q + w * 1024]);
            gload16(B + srcOff + (size_t)cn * 128, &lds[q + 16384 + w * 1024]);
            asm volatile("s_waitcnt vmcnt(2)" ::: "memory");  // chunk c landed
        } else {
            asm volatile("s_waitcnt vmcnt(0)" ::: "memory");
        }
        __builtin_amdgcn_s_barrier();          // everyone's writes visible
        asm volatile("" ::: "memory");

        const int pb = p * 32768;

        // sum-of-squares: this wave's own 8 rows (lane reads its staged slot)
        {
            f32x4 va = *(const f32x4*)&lds[pb + myrow * 128 + (sslt << 4)];
            f32x4 vb = *(const f32x4*)&lds[pb + 16384 + myrow * 128 + (sslt << 4)];
            sqa += va[0]*va[0] + va[1]*va[1] + va[2]*va[2] + va[3]*va[3];
            sqb += vb[0]*vb[0] + vb[1]*vb[1] + vb[2]*vb[2] + vb[3]*vb[3];
        }

        // fragments: row m/n, logical slots grp*2, grp*2+1, XOR-unswizzle
        short8 af[2], bfg[2];
        #pragma unroll
        for (int tm = 0; tm < 2; tm++) {
            int m = wrow * 32 + tm * 16 + fr;
            int s0 = grp * 2;
            f32x4 x0 = *(const f32x4*)&lds[pb + m * 128 + (((s0    ) ^ (m & 7)) << 4)];
            f32x4 x1 = *(const f32x4*)&lds[pb + m * 128 + (((s0 + 1) ^ (m & 7)) << 4)];
            af[tm] = cvt8(x0, x1);
        }
        #pragma unroll
        for (int tn = 0; tn < 2; tn++) {
            int n = wcol * 32 + tn * 16 + fr;
            int s0 = grp * 2;
            f32x4 x0 = *(const f32x4*)&lds[pb + 16384 + n * 128 + (((s0    ) ^ (n & 7)) << 4)];
            f32x4 x1 = *(const f32x4*)&lds[pb + 16384 + n * 128 + (((s0 + 1) ^ (n & 7)) << 4)];
            bfg[tn] = cvt8(x0, x1);
        }
        #pragma unroll
        for (int tm = 0; tm < 2; tm++)
            #pragma unroll
            for (int tn = 0; tn < 2; tn++)
                acc[tm][tn] = __builtin_amdgcn_mfma_f32_16x16x32_bf16(
                    af[tm], bfg[tn], acc[tm][tn], 0, 0, 0);

        __builtin_amdgcn_s_barrier();   // reads done; buf[p] reusable
        p ^= 1;
        c = cn;
    }

    // ---- epilogue: acc -> LDS f32 [128][128], then 255 diagonal sums ----
    __syncthreads();
    float* ldsF = (float*)lds;
    const int crow = grp * 4, ccol = fr;   // C/D: col=lane&15, row=(lane>>4)*4+reg
    #pragma unroll
    for (int tm = 0; tm < 2; tm++)
        #pragma unroll
        for (int tn = 0; tn < 2; tn++) {
            int row0 = wrow * 32 + tm * 16 + crow;
            int col  = wcol * 32 + tn * 16 + ccol;
            #pragma unroll
            for (int rg = 0; rg < 4; rg++)
                ldsF[(row0 + rg) * 128 + col] = acc[tm][tn][rg];
        }
    __syncthreads();

    if (t < 255) {
        int del = t - 127;                   // col - row
        int r0  = del < 0 ? -del : 0;
        int len = 128 - (del < 0 ? -del : del);
        float s = 0.f;
        for (int i = 0; i < len; i++) {
            int r = r0 + i;
            s += ldsF[r * 128 + r + del];    // stride 129: conflict-free
        }
        atomicAdd(&diag[t], s);
    }

    // sq: reduce the 8 lanes sharing a row, one atomic per row per block
    sqa += __shfl_xor(sqa, 1); sqa += __shfl_xor(sqa, 2); sqa += __shfl_xor(sqa, 4);
    sqb += __shfl_xor(sqb, 1); sqb += __shfl_xor(sqb, 2); sqb += __shfl_xor(sqb, 4);
    if ((l & 7) == 0) {
        atomicAdd(&sqBuf[myrow], sqa);
        atomicAdd(&sqBuf[128 + myrow], sqb);
    }
}

// K3: combine diag gram sums with sq-norm terms -> 129 outputs.
__global__ void k3_out(const float* __restrict__ sqBuf,
                       const float* __restrict__ diag,
                       float* __restrict__ out)
{
    int o = threadIdx.x;
    if (o >= 129) return;
    int d   = o - 64;
    int ad  = d < 0 ? -d : d;
    int cnt = 128 - ad;
    int i0  = d < 0 ? -d : 0;
    float sq = 0.f;
    for (int tt = 0; tt < cnt; tt++) {
        int i = i0 + tt;
        sq += sqBuf[i] + sqBuf[128 + i + d];
    }
    float gv = diag[63 + o];
    out[o] = -((sq - 2.f * gv) * (1.0f / (float)DFEAT)) * 1e13f / (float)cnt;
}

extern "C" void kernel_launch(void* const* d_in, const int* in_sizes, int n_in,
                              void* d_out, int out_size, void* d_ws, size_t ws_size,
                              hipStream_t stream) {
    const char* clip1 = (const char*)d_in[0];  // b: matrix cols (y)
    const char* clip2 = (const char*)d_in[1];  // a: matrix rows (x)
    float* out = (float*)d_out;

    float* sqBuf = (float*)d_ws;          // 256 floats
    float* diag  = sqBuf + 256;           // 255 floats

    hipMemsetAsync(d_ws, 0, 4096, stream);
    k1_gram<<<dim3(GRID), dim3(1024), 0, stream>>>(clip2, clip1, diag, sqBuf);
    k3_out<<<dim3(1), dim3(256), 0, stream>>>(sqBuf, diag, out);
}